// Round 2
// baseline (201.036 us; speedup 1.0000x reference)
//
#include <hip/hip_runtime.h>

// RQS (rational-quadratic spline) transform, 8192x2048 f32, K=8 bins.
// R1: 82us kernel, VALU-bound at the time (old heavy select chain).
// R3 FAILED: __launch_bounds__(256,8) VGPR cap -> table spills (FETCH 33->295MB).
// R4: (256,4), plain float2 IO. Kernel <78us (below harness fills in rocprof).
// R5 NEUTRAL: cndmask-chain -> LDS (ch,dv) gather + idx arithmetic. Harness
//   200.3->199.4. Post-mortem: kernel is MEMORY-bound (~44us vs 33us HBM floor;
//   VALU floor only ~12us). Harness dur includes ~156us of 512-MiB poison
//   fills -- kernel-side VALU cuts are invisible.
// R6: attack the memory side: 16B/lane IO (the m13 max-BW pattern).
//   Process 2 rows/iter; even lanes load row r float4 (4 dims), odd lanes
//   row r+1; three 8B __shfl_xor(1) swaps redistribute so each thread still
//   evaluates only its own 2 dims. Memory instr count halves. Tables
//   unchanged: cw[9] in VGPRs, (ch,dv) pairs in LDS (36,864 B/block).

constexpr int   KBINS = 8;
constexpr float TAILF = 3.0f;
constexpr float MINW  = 0.001f;
constexpr float MINH  = 0.001f;
constexpr float MIND  = 0.001f;
constexpr int   NROWS = 8192;
constexpr int   NDIM  = 2048;
constexpr int   NPAR  = 3 * KBINS - 1;  // 23
constexpr int   VEC   = 2;              // dims OWNED per thread (tables)
constexpr int   BLOCK = 256;
constexpr int   DIMS_PER_BLOCK = BLOCK * VEC;           // 512
constexpr int   BLOCKS_PER_ROW = NDIM / DIMS_PER_BLOCK; // 4
constexpr int   GROWS = 512;                            // parallel row walkers
constexpr int   ROWS_PER_WALK = NROWS / GROWS;          // 16

typedef float v2f __attribute__((ext_vector_type(2)));
typedef float v4f __attribute__((ext_vector_type(4)));

__device__ __forceinline__ float rcp_fast(float x) {
    return __builtin_amdgcn_rcpf(x);  // v_rcp_f32, ~1 ulp
}

// fast softplus: max(x,0) + log(1+exp(-|x|)) with v_exp/v_log
__device__ __forceinline__ float softplus_fast(float x) {
    return fmaxf(x, 0.0f) + __logf(1.0f + __expf(-fabsf(x)));
}

// 8-byte lane-pair exchange: swap a float2 with lane^1 (2x ds_swizzle_b32)
__device__ __forceinline__ v2f shfl_xor1_f2(v2f v) {
    double d = __builtin_bit_cast(double, v);
    d = __shfl_xor(d, 1, 64);
    return __builtin_bit_cast(v2f, d);
}

// Evaluate one element. cw = 9 knot x-positions in VGPRs; tab = LDS row of
// (ch[k], dv[k]) pairs for this dim.
__device__ __forceinline__ void rqs_eval(float x, const float* __restrict__ cw,
                                         const v2f* __restrict__ tab,
                                         float& o, float& ld) {
    const float xi = __builtin_amdgcn_fmed3f(x, -TAILF, TAILF);  // clamp, 1 op
    float icw = cw[0], ncw = cw[1];
    int idx = 0;
#pragma unroll
    for (int k = 1; k < KBINS; ++k) {
        const bool c = xi >= cw[k];
        icw = c ? cw[k]     : icw;
        ncw = c ? cw[k + 1] : ncw;
        idx += c ? 1 : 0;
    }
    // gather (ich,dlo) and (nch,dhi) from LDS: 2x ds_read_b64
    const v2f lo = tab[idx];
    const v2f hi = tab[idx + 1];
    const float ich = lo.x, dlo = lo.y;
    const float nch = hi.x, dhi = hi.y;

    const float iw  = ncw - icw;
    const float ih  = nch - ich;
    const float riw = rcp_fast(iw);
    const float delta = ih * riw;
    const float theta = (xi - icw) * riw;
    const float omt   = 1.0f - theta;
    const float t1m   = theta * omt;
    const float th2   = theta * theta;
    const float num   = ih * fmaf(delta, th2, dlo * t1m);
    const float den   = fmaf(dlo + dhi - 2.0f * delta, t1m, delta);
    const float rden  = rcp_fast(den);
    const float o_in  = fmaf(num, rden, ich);
    const float dn    = (delta * delta) *
                        fmaf(dhi, th2, fmaf(2.0f * delta, t1m, dlo * (omt * omt)));
    // log(dn) - 2 log(den) == log(dn * rden * rden): ONE fast log
    const float ld_in = __logf(dn * rden * rden);
    const bool inside = fabsf(x) <= TAILF;  // |x| is a free input modifier
    o  = inside ? o_in : x;
    ld = inside ? ld_in : 0.0f;
}

__global__ __launch_bounds__(BLOCK, 4)
void rqs_kernel(const float* __restrict__ inp,
                const float* __restrict__ params,
                float* __restrict__ out) {
    // (ch[k], dv[k]) pairs per local dim: 512 * 9 * 8 B = 36,864 B
    __shared__ v2f chdv[DIMS_PER_BLOCK][KBINS + 1];

    const int b        = blockIdx.x;
    const int colBlock = b & (BLOCKS_PER_ROW - 1);
    const int rowGroup = b / BLOCKS_PER_ROW;
    const int l0   = (int)threadIdx.x * VEC;          // local dim index (owned)
    const int d0   = colBlock * DIMS_PER_BLOCK + l0;  // global dim index
    const int row0 = rowGroup * ROWS_PER_WALK;

    const float edge_deriv = MIND + softplus_fast(__logf(__expf(1.0f - MIND) - 1.0f));

    float cw[VEC][KBINS + 1];
#pragma unroll
    for (int v = 0; v < VEC; ++v) {
        const float* __restrict__ p = params + (size_t)(d0 + v) * NPAR;
        // widths -> cw knots (stay in registers: needed by the compare chain)
        {
            float u[KBINS];
            float m = p[0];
#pragma unroll
            for (int k = 1; k < KBINS; ++k) m = fmaxf(m, p[k]);
            float s = 0.0f;
#pragma unroll
            for (int k = 0; k < KBINS; ++k) { u[k] = __expf(p[k] - m); s += u[k]; }
            const float scale = (1.0f - MINW * KBINS) * rcp_fast(s);
            cw[v][0] = -TAILF;
            float acc = 0.0f;
#pragma unroll
            for (int k = 0; k < KBINS - 1; ++k) {
                acc += MINW + scale * u[k];
                cw[v][k + 1] = fmaf(2.0f * TAILF, acc, -TAILF);
            }
            cw[v][KBINS] = TAILF;
        }
        // heights + derivatives -> LDS (ch[k], dv[k]) pairs
        {
            const float* __restrict__ q = p + KBINS;
            float u[KBINS];
            float m = q[0];
#pragma unroll
            for (int k = 1; k < KBINS; ++k) m = fmaxf(m, q[k]);
            float s = 0.0f;
#pragma unroll
            for (int k = 0; k < KBINS; ++k) { u[k] = __expf(q[k] - m); s += u[k]; }
            const float scale = (1.0f - MINH * KBINS) * rcp_fast(s);
            v2f e0; e0.x = -TAILF; e0.y = edge_deriv;
            chdv[l0 + v][0] = e0;
            float acc = 0.0f;
#pragma unroll
            for (int k = 0; k < KBINS; ++k) {
                acc += MINH + scale * u[k];
                v2f e;
                e.x = (k == KBINS - 1) ? TAILF
                                       : fmaf(2.0f * TAILF, acc, -TAILF);
                // interior knot k+1 uses params[2K + (k+1) - 1] = p[16 + k]
                e.y = (k == KBINS - 1) ? edge_deriv
                                       : MIND + softplus_fast(p[2 * KBINS + k]);
                chdv[l0 + v][k + 1] = e;
            }
        }
    }
    __syncthreads();

    const v2f* __restrict__ tab0 = &chdv[l0][0];
    const v2f* __restrict__ tab1 = &chdv[l0 + 1][0];

    // 16B/lane IO: even lanes handle row r, odd lanes row r+1, with 8B
    // lane-pair exchanges so each thread evaluates only its owned dims.
    const int  par      = (int)threadIdx.x & 1;
    const int  pairCol  = colBlock * DIMS_PER_BLOCK +
                          (((int)threadIdx.x >> 1) << 2);  // float idx of float4
    const v4f* __restrict__ in4  = (const v4f*)inp;
    v4f* __restrict__       out4 = (v4f*)out;
    v4f* __restrict__       ld4  = (v4f*)(out + (size_t)NROWS * NDIM);

#pragma unroll 4
    for (int r = 0; r < ROWS_PER_WALK; r += 2) {
        const int myrow = row0 + r + par;
        const size_t i4 = ((size_t)myrow * NDIM + pairCol) >> 2;
        const v4f xv = in4[i4];

        // input exchange: even sends row r dims(+2,+3); odd sends row r+1 dims(+0,+1)
        v2f s_in;
        s_in.x = par ? xv.x : xv.z;
        s_in.y = par ? xv.y : xv.w;
        const v2f r_in = shfl_xor1_f2(s_in);
        // own-dim inputs for rowA = row0+r and rowB = row0+r+1
        v2f xa, xb;
        xa.x = par ? r_in.x : xv.x;
        xa.y = par ? r_in.y : xv.y;
        xb.x = par ? xv.z : r_in.x;
        xb.y = par ? xv.w : r_in.y;

        float oa0, la0, oa1, la1, ob0, lb0, ob1, lb1;
        rqs_eval(xa.x, cw[0], tab0, oa0, la0);
        rqs_eval(xa.y, cw[1], tab1, oa1, la1);
        rqs_eval(xb.x, cw[0], tab0, ob0, lb0);
        rqs_eval(xb.y, cw[1], tab1, ob1, lb1);

        // output exchange: even sends rowB pair (for odd's store of row r+1);
        // odd sends rowA pair (for even's store of row r)
        v2f so; so.x = par ? oa0 : ob0; so.y = par ? oa1 : ob1;
        const v2f ro = shfl_xor1_f2(so);
        v2f sl; sl.x = par ? la0 : lb0; sl.y = par ? la1 : lb1;
        const v2f rl = shfl_xor1_f2(sl);

        v4f ov, lv;
        ov.x = par ? ro.x : oa0;  ov.y = par ? ro.y : oa1;
        ov.z = par ? ob0  : ro.x; ov.w = par ? ob1  : ro.y;
        lv.x = par ? rl.x : la0;  lv.y = par ? rl.y : la1;
        lv.z = par ? lb0  : rl.x; lv.w = par ? lb1  : rl.y;

        out4[i4] = ov;
        ld4[i4]  = lv;
    }
}

extern "C" void kernel_launch(void* const* d_in, const int* in_sizes, int n_in,
                              void* d_out, int out_size, void* d_ws, size_t ws_size,
                              hipStream_t stream) {
    const float* inp    = (const float*)d_in[0];
    const float* params = (const float*)d_in[1];
    float* out          = (float*)d_out;
    rqs_kernel<<<BLOCKS_PER_ROW * GROWS, BLOCK, 0, stream>>>(inp, params, out);
}